// Round 11
// baseline (6062.371 us; speedup 1.0000x reference)
//
#include <hip/hip_runtime.h>
#include <hip/hip_fp16.h>

#define DM   256      // d_model
#define DI   512      // d_inner
#define TG   768      // 3*d_model
#define TSEQ 4096
#define NB   8
#define MTOT (NB*TSEQ) // 32768

typedef _Float16 f16x4 __attribute__((ext_vector_type(4)));
typedef _Float16 f16x8 __attribute__((ext_vector_type(8)));
typedef float    f32x4 __attribute__((ext_vector_type(4)));

// ---------------- Phase 1: tiled fp32 GEMM, C = act(A @ W^T + bias) in fp16 ----
// TNB_OUT: scatter-store C as [t][n][b] f16 (for the scan's gate loads).
template<bool A_HALF, bool GELU_ACT, bool TNB_OUT>
__global__ __launch_bounds__(256) void gemm_bias(
    const void* __restrict__ Ap, const float* __restrict__ W,
    const float* __restrict__ bias, __half* __restrict__ C,
    int M, int N, int K)
{
  __shared__ float As[16][132];   // transposed: [k][m]
  __shared__ float Ws[16][132];   // transposed: [k][n]
  const int tid = threadIdx.x;
  const int tx = tid & 15, ty = tid >> 4;
  const int m0 = blockIdx.y * 128;
  const int n0 = blockIdx.x * 128;

  float acc[8][8] = {};

  for (int k0 = 0; k0 < K; k0 += 16) {
    if constexpr (A_HALF) {
      const __half* A = (const __half*)Ap;
      int r = tid >> 1, seg = (tid & 1) * 8;
      float4 raw = *(const float4*)(A + (size_t)(m0 + r) * K + k0 + seg);
      const __half* hv = (const __half*)&raw;
      #pragma unroll
      for (int q = 0; q < 8; q++) As[seg + q][r] = __half2float(hv[q]);
    } else {
      const float* A = (const float*)Ap;
      #pragma unroll
      for (int rep = 0; rep < 2; rep++) {
        int r = (tid >> 2) + rep * 64;
        int seg = (tid & 3) * 4;
        float4 v = *(const float4*)(A + (size_t)(m0 + r) * K + k0 + seg);
        As[seg + 0][r] = v.x; As[seg + 1][r] = v.y;
        As[seg + 2][r] = v.z; As[seg + 3][r] = v.w;
      }
    }
    #pragma unroll
    for (int rep = 0; rep < 2; rep++) {
      int r = (tid >> 2) + rep * 64;
      int seg = (tid & 3) * 4;
      float4 v = *(const float4*)(W + (size_t)(n0 + r) * K + k0 + seg);
      Ws[seg + 0][r] = v.x; Ws[seg + 1][r] = v.y;
      Ws[seg + 2][r] = v.z; Ws[seg + 3][r] = v.w;
    }
    __syncthreads();
    #pragma unroll
    for (int kk = 0; kk < 16; ++kk) {
      float a[8], b[8];
      *(float4*)&a[0] = *(const float4*)&As[kk][ty * 8];
      *(float4*)&a[4] = *(const float4*)&As[kk][ty * 8 + 4];
      *(float4*)&b[0] = *(const float4*)&Ws[kk][tx * 8];
      *(float4*)&b[4] = *(const float4*)&Ws[kk][tx * 8 + 4];
      #pragma unroll
      for (int i = 0; i < 8; i++)
        #pragma unroll
        for (int j = 0; j < 8; j++)
          acc[i][j] += a[i] * b[j];
    }
    __syncthreads();
  }

  #pragma unroll
  for (int i = 0; i < 8; i++) {
    int m = m0 + ty * 8 + i;
    #pragma unroll
    for (int j = 0; j < 8; j++) {
      int n = n0 + tx * 8 + j;
      float v = acc[i][j] + bias[n];
      if constexpr (GELU_ACT) {
        v = 0.5f * v * (1.0f + erff(v * 0.70710678118654752f));  // exact GELU
      }
      if constexpr (TNB_OUT) {
        // m = b*TSEQ + t  ->  gxbuf[t][n][b]
        C[((size_t)(m & (TSEQ - 1)) * TG + n) * NB + (m >> 12)] = __float2half(v);
      } else {
        C[(size_t)m * N + n] = __float2half(v);
      }
    }
  }
}

// ---------------- Phase 2: GRU scan via MFMA, ONE block, all 8 batches -------
// ROUND-10 LESSON: the compiler pins arch VGPRs at 128 and parks overflow in
// AGPRs; v_dot2 can't read AGPRs -> per-use v_accvgpr_read tax (the stable
// 2700cy/step across rounds 4-10). MFMA *can* read AGPRs natively, so hold
// W_hh as MFMA B-fragments (192 regs/wave in AGPR, zero moves) and compute
// gh[8,768] = h[8,256] @ W_hh^T as 48 mfma_f32_16x16x32_f16 per wave per step
// (batches = M rows 0..7; rows 8..15 zero).
// Wave w owns N-tiles {w, w+8, w+16, w+24, w+32, w+40}: its r/z/n tiles for
// the same 32 units land in the SAME lanes -> gates are wave-local; a 12-reg
// __shfl(lane^32) swap moves the 2nd col-group to the upper half-wave so all
// 64 lanes compute gates (4 hnew each).
// Layouts (A/B standard CDNA, C/D per m89): A: row=l&15, k=(l>>4)*8+j;
// B: col=l&15, k=(l>>4)*8+j (row of W_hh in consecutive k); D: col=l&15,
// row=(l>>4)*4+reg.
#define MFMA16(A, B, C) __builtin_amdgcn_mfma_f32_16x16x32_f16(A, B, C, 0, 0, 0)

#define LDB(NM, G, C, KT) f16x8 NM; { \
    const float* p_ = Whh + (size_t)(256*(G) + 16*((C)*8 + w) + col) * DM + (KT)*32 + kgrp*8; \
    float4 fa_ = *(const float4*)p_; float4 fb_ = *(const float4*)(p_ + 4);    \
    NM[0]=(_Float16)fa_.x; NM[1]=(_Float16)fa_.y; NM[2]=(_Float16)fa_.z; NM[3]=(_Float16)fa_.w; \
    NM[4]=(_Float16)fb_.x; NM[5]=(_Float16)fb_.y; NM[6]=(_Float16)fb_.z; NM[7]=(_Float16)fb_.w; }

#define LDB8(P, G, C) \
  LDB(P##0, G, C, 0) LDB(P##1, G, C, 1) LDB(P##2, G, C, 2) LDB(P##3, G, C, 3) \
  LDB(P##4, G, C, 4) LDB(P##5, G, C, 5) LDB(P##6, G, C, 6) LDB(P##7, G, C, 7)

#define MSTEP(RA, ZA, NA, BR, BZ, BN, KT) {                                    \
    f16x8 a_ = *(const f16x8*)&hb[cur][col][(KT)*32 + kgrp*8];                 \
    RA = MFMA16(a_, BR, RA); ZA = MFMA16(a_, BZ, ZA); NA = MFMA16(a_, BN, NA); }

__device__ __forceinline__ float selswap(float x, float y, int lane) {
  float ys = __shfl(y, lane ^ 32, 64);   // upper lanes fetch c1 data from l-32
  return (lane < 32) ? x : ys;
}

__global__ __attribute__((amdgpu_flat_work_group_size(512, 512)))
__attribute__((amdgpu_waves_per_eu(2, 2)))
void gru_scan(
    const __half* __restrict__ gxb,  // [T][768][8] f16 (includes b_ih)
    const float*  __restrict__ Whh,  // [768, 256]
    const float*  __restrict__ bhh,  // [768]
    float* __restrict__ out)         // [B, T, 256]
{
  const int tid  = threadIdx.x;        // 0..511
  const int w    = tid >> 6;           // wave 0..7
  const int lane = tid & 63;
  const int col  = lane & 15;          // B col / A row / D col
  const int kgrp = lane >> 4;          // 0..3 (k-slot group)
  const int ch   = lane >> 5;          // col-group this lane GATES (0/1)
  const int bb   = ((lane >> 4) & 1) * 4;  // batch base for gates

  __shared__ __align__(16) _Float16 hb[2][16][264];  // [buf][row=b][k=u], padded

  for (int i = tid; i < 2 * 16 * 264; i += 512) ((_Float16*)hb)[i] = (_Float16)0.0f;

  // ---- resident B-fragments: 48 x f16x8 (gate g, col-group c, K-tile kt) ----
  LDB8(bR0, 0, 0) LDB8(bZ0, 1, 0) LDB8(bN0, 2, 0)
  LDB8(bR1, 0, 1) LDB8(bZ1, 1, 1) LDB8(bN1, 2, 1)

  // gate-role constants for this lane
  const int u = 16 * (w + 8 * ch) + col;            // hidden unit 0..255
  const float brv = bhh[u];
  const float bzv = bhh[DM + u];
  const float bnv = bhh[2 * DM + u];
  float hl0 = 0.f, hl1 = 0.f, hl2 = 0.f, hl3 = 0.f;

  __syncthreads();

  const __half* gp = gxb + (size_t)u * NB + bb;     // t=0; stride 6144/step
  f16x4 gr_c = *(const f16x4*)(gp);
  f16x4 gz_c = *(const f16x4*)(gp + 2048);
  f16x4 gn_c = *(const f16x4*)(gp + 4096);

  for (int t = 0; t < TSEQ; ++t) {
    const int cur = t & 1, nxt = cur ^ 1;

    // prefetch next step's gx (lands during the MFMA block)
    const __half* gq = gp + ((t < TSEQ - 1) ? TG * NB : 0);
    f16x4 gr_n = *(const f16x4*)(gq);
    f16x4 gz_n = *(const f16x4*)(gq + 2048);
    f16x4 gn_n = *(const f16x4*)(gq + 4096);

    const f32x4 Zv = {0.f, 0.f, 0.f, 0.f};
    f32x4 R0 = Zv, Z0 = Zv, N0 = Zv;
    MSTEP(R0, Z0, N0, bR00, bZ00, bN00, 0) MSTEP(R0, Z0, N0, bR01, bZ01, bN01, 1)
    MSTEP(R0, Z0, N0, bR02, bZ02, bN02, 2) MSTEP(R0, Z0, N0, bR03, bZ03, bN03, 3)
    MSTEP(R0, Z0, N0, bR04, bZ04, bN04, 4) MSTEP(R0, Z0, N0, bR05, bZ05, bN05, 5)
    MSTEP(R0, Z0, N0, bR06, bZ06, bN06, 6) MSTEP(R0, Z0, N0, bR07, bZ07, bN07, 7)
    f32x4 R1 = Zv, Z1 = Zv, N1 = Zv;
    MSTEP(R1, Z1, N1, bR10, bZ10, bN10, 0) MSTEP(R1, Z1, N1, bR11, bZ11, bN11, 1)
    MSTEP(R1, Z1, N1, bR12, bZ12, bN12, 2) MSTEP(R1, Z1, N1, bR13, bZ13, bN13, 3)
    MSTEP(R1, Z1, N1, bR14, bZ14, bN14, 4) MSTEP(R1, Z1, N1, bR15, bZ15, bN15, 5)
    MSTEP(R1, Z1, N1, bR16, bZ16, bN16, 6) MSTEP(R1, Z1, N1, bR17, bZ17, bN17, 7)

    // ---- gates: all 64 lanes, 4 hnew each ----
    #define GATE(i, HL) {                                                      \
      float ghr = selswap(R0[i], R1[i], lane);                                 \
      float ghz = selswap(Z0[i], Z1[i], lane);                                 \
      float ghn = selswap(N0[i], N1[i], lane);                                 \
      float xr = (float)gr_c[i], xz = (float)gz_c[i], xn = (float)gn_c[i];     \
      float rg = __builtin_amdgcn_rcpf(1.0f + __expf(-(xr + ghr + brv)));      \
      float zg = __builtin_amdgcn_rcpf(1.0f + __expf(-(xz + ghz + bzv)));      \
      float ap = xn + rg * (ghn + bnv);                                        \
      float e  = __expf(-2.0f * __builtin_fabsf(ap));                          \
      float nn = __builtin_copysignf(                                          \
          (1.0f - e) * __builtin_amdgcn_rcpf(1.0f + e), ap);                   \
      float hnew = nn + zg * (HL - nn);                                        \
      HL = hnew;                                                               \
      hb[nxt][bb + (i)][u] = (_Float16)hnew;                                   \
      out[((size_t)(bb + (i)) * TSEQ + t) * DM + u] = hnew;                    \
    }
    GATE(0, hl0) GATE(1, hl1) GATE(2, hl2) GATE(3, hl3)
    #undef GATE

    __syncthreads();   // h writes (buf nxt) visible before next step's reads

    gp = gq;
    gr_c = gr_n; gz_c = gz_n; gn_c = gn_n;
  }
}

extern "C" void kernel_launch(void* const* d_in, const int* in_sizes, int n_in,
                              void* d_out, int out_size, void* d_ws, size_t ws_size,
                              hipStream_t stream) {
  const float* x   = (const float*)d_in[0];
  const float* W1  = (const float*)d_in[1];
  const float* b1  = (const float*)d_in[2];
  const float* Wih = (const float*)d_in[3];
  const float* bih = (const float*)d_in[4];
  const float* Whh = (const float*)d_in[5];
  const float* bhh = (const float*)d_in[6];
  float* out = (float*)d_out;

  char* ws = (char*)d_ws;
  __half* h  = (__half*)ws;                                   // [32768,512] fp16
  size_t h_bytes = (size_t)MTOT * DI * sizeof(__half);
  h_bytes = (h_bytes + 255) & ~(size_t)255;
  __half* gxbuf = (__half*)(ws + h_bytes);                    // [T][768][8] fp16

  dim3 blk(256);
  // h = gelu(x @ W1^T + b1), row-major [b*T+t][512]
  gemm_bias<false, true, false><<<dim3(DI / 128, MTOT / 128), blk, 0, stream>>>(
      x, W1, b1, h, MTOT, DI, DM);
  // gx = h @ W_ih^T + b_ih, scattered to [t][768][8]
  gemm_bias<true, false, true><<<dim3(TG / 128, MTOT / 128), blk, 0, stream>>>(
      h, Wih, bih, gxbuf, MTOT, TG, DI);
  // GRU scan: one block, all batches via MFMA M-rows
  gru_scan<<<1, 512, 0, stream>>>(gxbuf, Whh, bhh, out);
}